// Round 3
// baseline (58.178 us; speedup 1.0000x reference)
//
#include <hip/hip_runtime.h>
#include <math.h>

// SeesawLoss forward: B=8192 rows, C=4096 classes, P=0.8, Q=2.0, EPS=0.01
// out = mean_b [ M2_b + log(sum_j exp(logit_bj - M2_b)) - o_{b,t_b} ]
// logit_bj = o_bj + P*(la_j - la_t)[la_j<la_t] + Q*(ls_j - logclip)[>0]

#define CC 4096

__device__ __forceinline__ float wave_max(float v) {
    #pragma unroll
    for (int o = 32; o > 0; o >>= 1) v = fmaxf(v, __shfl_xor(v, o, 64));
    return v;
}
__device__ __forceinline__ float wave_sum(float v) {
    #pragma unroll
    for (int o = 32; o > 0; o >>= 1) v += __shfl_xor(v, o, 64);
    return v;
}

__global__ __launch_bounds__(256) void k_zero(int* acc) {
    int i = blockIdx.x * 256 + threadIdx.x;
    if (i < CC) acc[i] = 0;
}

__global__ __launch_bounds__(256) void k_bincount(const int* __restrict__ tg,
                                                  int* __restrict__ acc, int B) {
    int i = blockIdx.x * 256 + threadIdx.x;
    if (i < B) atomicAdd(&acc[tg[i]], 1);
}

__global__ __launch_bounds__(256) void k_logacc(const int* __restrict__ acc,
                                                float* __restrict__ la) {
    int i = blockIdx.x * 256 + threadIdx.x;
    if (i < CC) {
        int a = acc[i];
        if (a < 1) a = 1;            // clamp(min=1)
        la[i] = __logf((float)a);
    }
}

__global__ __launch_bounds__(256) void k_row(const float* __restrict__ outp,
                                             const int* __restrict__ tg,
                                             const float* __restrict__ logacc,
                                             float* __restrict__ nll) {
    __shared__ float row[CC];   // 16 KB: staged outputs row
    __shared__ float lgt[CC];   // 16 KB: logits
    __shared__ float red[4];    // cross-wave reduce (4 waves of 64)

    const int b   = blockIdx.x;
    const int tid = threadIdx.x;
    const int w   = tid >> 6;
    const bool lane0 = (tid & 63) == 0;

    constexpr float P_ = 0.8f, Q_ = 2.0f;
    const float LOG_EPS = -4.605170185988091f;  // log(0.01)

    // ---- load row -> LDS, partial max (vectorized float4) ----
    const float4* src  = (const float4*)(outp + (size_t)b * CC);
    float4*       dst4 = (float4*)row;
    float m = -1e30f;
    #pragma unroll
    for (int k = 0; k < CC / 4 / 256; ++k) {
        int i = tid + k * 256;
        float4 v = src[i];
        dst4[i] = v;
        m = fmaxf(m, fmaxf(fmaxf(v.x, v.y), fmaxf(v.z, v.w)));
    }
    m = wave_max(m);
    if (lane0) red[w] = m;
    __syncthreads();                                   // row complete + red ready
    const float M = fmaxf(fmaxf(red[0], red[1]), fmaxf(red[2], red[3]));
    __syncthreads();                                   // done reading red

    // ---- pass 2: sum exp(o - M) ----
    float s = 0.f;
    #pragma unroll
    for (int k = 0; k < CC / 256; ++k) {
        int i = tid + k * 256;
        s += __expf(row[i] - M);
    }
    s = wave_sum(s);
    if (lane0) red[w] = s;
    __syncthreads();
    const float S = red[0] + red[1] + red[2] + red[3];
    const float lse1 = __logf(S);

    const int   t       = tg[b];
    const float o_t     = row[t];                      // LDS broadcast
    const float ls_t    = o_t - M - lse1;              // log self-score
    const float logclip = fmaxf(ls_t, LOG_EPS);        // log(max(self, EPS))
    const float la_t    = logacc[t];
    __syncthreads();                                   // done reading red

    // ---- pass 3: logits -> LDS, partial max ----
    // at j==t both predicates are exactly false -> extra == 0 (matches (1-onehot))
    float m2 = -1e30f;
    #pragma unroll
    for (int k = 0; k < CC / 256; ++k) {
        int i = tid + k * 256;
        float o  = row[i];
        float ls = o - M - lse1;
        float la = logacc[i];
        float extra = (la < la_t) ? P_ * (la - la_t) : 0.f;   // mitigation (<=0)
        float d = ls - logclip;
        extra += (d > 0.f) ? Q_ * d : 0.f;                    // compensation (>=0)
        float lg = o + extra;
        lgt[i] = lg;
        m2 = fmaxf(m2, lg);
    }
    m2 = wave_max(m2);
    if (lane0) red[w] = m2;
    __syncthreads();                                   // lgt complete + red ready
    const float M2 = fmaxf(fmaxf(red[0], red[1]), fmaxf(red[2], red[3]));
    __syncthreads();

    // ---- pass 4: sum exp(logit - M2) ----
    float s2 = 0.f;
    #pragma unroll
    for (int k = 0; k < CC / 256; ++k) {
        int i = tid + k * 256;
        s2 += __expf(lgt[i] - M2);
    }
    s2 = wave_sum(s2);
    if (lane0) red[w] = s2;
    __syncthreads();
    if (tid == 0) {
        float S2 = red[0] + red[1] + red[2] + red[3];
        nll[b] = M2 + __logf(S2) - o_t;
    }
}

// deterministic final mean: fixed strided partials + fixed tree
__global__ __launch_bounds__(256) void k_reduce(const float* __restrict__ nll,
                                                float* __restrict__ out, int B) {
    __shared__ float red[4];
    int tid = threadIdx.x;
    float s = 0.f;
    for (int i = tid; i < B; i += 256) s += nll[i];
    s = wave_sum(s);
    if ((tid & 63) == 0) red[tid >> 6] = s;
    __syncthreads();
    if (tid == 0) out[0] = (red[0] + red[1] + red[2] + red[3]) / (float)B;
}

extern "C" void kernel_launch(void* const* d_in, const int* in_sizes, int n_in,
                              void* d_out, int out_size, void* d_ws, size_t ws_size,
                              hipStream_t stream) {
    const float* outp = (const float*)d_in[0];   // [B, C] f32
    const int*   tg   = (const int*)d_in[1];     // [B] i32
    float*       out  = (float*)d_out;           // scalar f32

    const int B = in_sizes[1];                   // 8192 (C fixed at 4096)

    char*  ws     = (char*)d_ws;
    int*   acc    = (int*)ws;                    // 16 KB
    float* logacc = (float*)(ws + 16384);        // 16 KB
    float* nll    = (float*)(ws + 32768);        // B*4 = 32 KB

    k_zero    <<<(CC + 255) / 256, 256, 0, stream>>>(acc);
    k_bincount<<<(B  + 255) / 256, 256, 0, stream>>>(tg, acc, B);
    k_logacc  <<<(CC + 255) / 256, 256, 0, stream>>>(acc, logacc);
    k_row     <<<B, 256, 0, stream>>>(outp, tg, logacc, nll);
    k_reduce  <<<1, 256, 0, stream>>>(nll, out, B);
}